// Round 8
// baseline (313.113 us; speedup 1.0000x reference)
//
#include <hip/hip_runtime.h>
#include <math.h>

#define EPSF 0.3f
#define NPB 128      // nodes per row-bucket
#define SHB 7        // log2(NPB)
#define CBSH 13      // log2(col-block nodes) -> 8192 nodes = 2MB of hb rows
#define MAXK 4096    // max sort keys (rowbuckets * colblocks)
#define CHUNK 4096   // edges per block in hist/binwrite

typedef __attribute__((ext_vector_type(8))) short bf16x8;
typedef __attribute__((ext_vector_type(4))) float f32x4;

// ---------------- bf16 helpers ----------------
__device__ __forceinline__ uint32_t f2bf(float f) {
    uint32_t u = __float_as_uint(f);
    return (u + 0x7fffu + ((u >> 16) & 1u)) >> 16;  // RNE
}
__device__ __forceinline__ uint32_t pack2(float lo, float hi) {
    return f2bf(lo) | (f2bf(hi) << 16);
}
__device__ __forceinline__ float bflo(uint32_t u) { return __uint_as_float(u << 16); }
__device__ __forceinline__ float bfhi(uint32_t u) { return __uint_as_float(u & 0xffff0000u); }

// fast tanh: 1 - 2/(e^{2x}+1); v_exp-based, |err| ~1e-6, saturates correctly
__device__ __forceinline__ float fast_tanh(float x) {
    float e = __expf(2.f * x);
    return 1.f - 2.f * __builtin_amdgcn_rcpf(e + 1.f);
}

__device__ __forceinline__ int edge_at(const int* ei, int is64, size_t idx) {
    if (is64) return (int)((const long long*)ei)[idx];
    return ei[idx];
}

// per-block int32/int64 detection: sample odd dwords of this block's row slice
__device__ __forceinline__ int detect_is64(const int* ei, int base, int E) {
    __shared__ int s_nz;
    if (threadIdx.x == 0) s_nz = 0;
    __syncthreads();
    int lim = min(512, E - base);
    int nz = 0;
    for (int t = threadIdx.x; t < lim; t += 256)
        nz |= (ei[2 * (size_t)(base + t) + 1] != 0);
    if (nz) atomicOr(&s_nz, 1);
    __syncthreads();
    return s_nz == 0;
}

// ---------------- key histogram: hist[blk][key], key = rowbucket*NCB + (col>>CBSH) ----
__global__ __launch_bounds__(256) void k_hist(const int* __restrict__ ei, int E,
                                              int* __restrict__ hist, int nkeys, int NCB) {
    __shared__ int lh[MAXK];
    int base = blockIdx.x * CHUNK;
    int is64 = detect_is64(ei, base, E);
    for (int b = threadIdx.x; b < nkeys; b += 256) lh[b] = 0;
    __syncthreads();
    for (int j = threadIdx.x; j < CHUNK; j += 256) {
        int e = base + j;
        if (e < E) {
            int r = edge_at(ei, is64, e);
            int c = edge_at(ei, is64, (size_t)E + e);
            atomicAdd(&lh[(r >> SHB) * NCB + (c >> CBSH)], 1);
        }
    }
    __syncthreads();
    int* hrow = hist + (size_t)blockIdx.x * nkeys;
    for (int b = threadIdx.x; b < nkeys; b += 256) hrow[b] = lh[b];
}

// per-key exclusive scan across blocks (lane per key, serial over blk; coalesced)
__global__ void k_scanA(int* __restrict__ hist, int nblk, int nkeys,
                        int* __restrict__ btot) {
    int key = blockIdx.x * 64 + threadIdx.x;
    if (key >= nkeys) return;
    int run = 0;
    for (int blk = 0; blk < nblk; ++blk) {
        size_t idx = (size_t)blk * nkeys + key;
        int v = hist[idx];
        hist[idx] = run;
        run += v;
    }
    btot[key] = run;
}

// exclusive scan over key totals -> bbase[0..nkeys] (chunked single block)
__global__ void k_scanB(const int* __restrict__ btot, int n, int* __restrict__ bbase) {
    __shared__ int s[256];
    __shared__ int carry;
    if (threadIdx.x == 0) carry = 0;
    __syncthreads();
    for (int base = 0; base < n; base += 256) {
        int idx = base + threadIdx.x;
        int v = (idx < n) ? btot[idx] : 0;
        s[threadIdx.x] = v;
        __syncthreads();
        for (int o = 1; o < 256; o <<= 1) {
            int x = (threadIdx.x >= o) ? s[threadIdx.x - o] : 0;
            __syncthreads();
            s[threadIdx.x] += x;
            __syncthreads();
        }
        if (idx < n) bbase[idx] = carry + s[threadIdx.x] - v;
        int tot = s[255];
        __syncthreads();
        if (threadIdx.x == 0) carry += tot;
        __syncthreads();
    }
    if (threadIdx.x == 0) bbase[n] = carry;
}

// packed ebuf entry: (r & 127) | (c << 7)
__global__ __launch_bounds__(256) void k_binwrite(const int* __restrict__ ei, int E,
                                                  const int* __restrict__ hist,
                                                  const int* __restrict__ bbase,
                                                  uint32_t* __restrict__ ebuf,
                                                  int nkeys, int NCB) {
    __shared__ int lcnt[MAXK];
    int base = blockIdx.x * CHUNK;
    int is64 = detect_is64(ei, base, E);
    const int* hrow = hist + (size_t)blockIdx.x * nkeys;
    for (int b = threadIdx.x; b < nkeys; b += 256)
        lcnt[b] = bbase[b] + hrow[b];
    __syncthreads();
    for (int j = threadIdx.x; j < CHUNK; j += 256) {
        int e = base + j;
        if (e < E) {
            int r = edge_at(ei, is64, e);
            int c = edge_at(ei, is64, (size_t)E + e);
            int pos = atomicAdd(&lcnt[(r >> SHB) * NCB + (c >> CBSH)], 1);
            ebuf[pos] = (uint32_t)(r & (NPB - 1)) | ((uint32_t)c << SHB);
        }
    }
}

// one block per row-bucket (= NCB consecutive key segments, already col-block ordered)
__global__ __launch_bounds__(256) void k_csr(const uint32_t* __restrict__ ebuf,
                                             const int* __restrict__ bbase,
                                             int* __restrict__ rp, float* __restrict__ dinv,
                                             int* __restrict__ ecol, int N, int E,
                                             int NB, int NCB) {
    __shared__ int cnt[NPB];
    __shared__ int sc[NPB];
    __shared__ int cur[NPB];
    int b = blockIdx.x;
    int tid = threadIdx.x;
    int p0 = bbase[b * NCB], p1 = bbase[b * NCB + NCB];
    int n0 = b << SHB;
    if (tid < NPB) cnt[tid] = 0;
    __syncthreads();
    for (int p = p0 + tid; p < p1; p += 256)
        atomicAdd(&cnt[ebuf[p] & (NPB - 1)], 1);
    __syncthreads();
    if (tid < NPB) sc[tid] = cnt[tid];
    __syncthreads();
    for (int o = 1; o < NPB; o <<= 1) {
        int v = (tid < NPB && tid >= o) ? sc[tid - o] : 0;
        __syncthreads();
        if (tid < NPB) sc[tid] += v;
        __syncthreads();
    }
    if (tid < NPB) {
        int off = sc[tid] - cnt[tid];
        cur[tid] = off;
        int node = n0 + tid;
        if (node < N) {
            rp[node] = p0 + off;
            int d = cnt[tid];
            dinv[node] = d > 0 ? rsqrtf((float)d) : 0.f;
        }
    }
    if (b == NB - 1 && tid == 0) rp[N] = E;
    __syncthreads();
    // scatter in p order: per-node lists come out col-block sorted (window ~256 scramble)
    for (int p = p0 + tid; p < p1; p += 256) {
        uint32_t v = ebuf[p];
        int pos = p0 + atomicAdd(&cur[v & (NPB - 1)], 1);
        ecol[pos] = (int)(v >> SHB);
    }
}

// ---------------- GEMM1 (MFMA bf16): hb = relu(x @ t1_w^T + b) as bf16 ----------------
__global__ __launch_bounds__(256) void k_gemm1(const float* __restrict__ A,
                                               const float* __restrict__ W,
                                               const float* __restrict__ bias,
                                               uint32_t* __restrict__ hb, int M) {
    __shared__ char As[128 * 128];
    __shared__ char Bs[128 * 128];
    const int tid = threadIdx.x;
    const int lane = tid & 63;
    const int wave = tid >> 6;
    const int wr = wave >> 1, wc = wave & 1;
    const int m0 = blockIdx.x * 128;
    const int lrow = lane & 15, lkg = lane >> 4;
    const int sr = tid >> 3;
    const int sc = (tid & 7) * 8;

    f32x4 acc[4][4];
#pragma unroll
    for (int mi = 0; mi < 4; ++mi)
#pragma unroll
        for (int ni = 0; ni < 4; ++ni) acc[mi][ni] = (f32x4){0.f, 0.f, 0.f, 0.f};

    for (int t = 0; t < 4; ++t) {
        const int k0 = t * 64;
#pragma unroll
        for (int i = 0; i < 4; ++i) {
            int r = i * 32 + sr;
            float4 v0 = make_float4(0.f, 0.f, 0.f, 0.f), v1 = v0;
            if (m0 + r < M) {
                const float* p = &A[(size_t)(m0 + r) * 256 + k0 + sc];
                v0 = *(const float4*)p;
                v1 = *(const float4*)(p + 4);
            }
            uint4 pk = make_uint4(pack2(v0.x, v0.y), pack2(v0.z, v0.w),
                                  pack2(v1.x, v1.y), pack2(v1.z, v1.w));
            uint32_t off = (uint32_t)(r * 128 + sc * 2);
            *(uint4*)(As + (off ^ ((r & 7) << 4))) = pk;
        }
#pragma unroll
        for (int i = 0; i < 4; ++i) {
            int r = i * 32 + sr;
            const float* p = &W[(size_t)r * 256 + k0 + sc];
            float4 v0 = *(const float4*)p;
            float4 v1 = *(const float4*)(p + 4);
            uint4 pk = make_uint4(pack2(v0.x, v0.y), pack2(v0.z, v0.w),
                                  pack2(v1.x, v1.y), pack2(v1.z, v1.w));
            uint32_t off = (uint32_t)(r * 128 + sc * 2);
            *(uint4*)(Bs + (off ^ ((r & 7) << 4))) = pk;
        }
        __syncthreads();
#pragma unroll
        for (int ks = 0; ks < 2; ++ks) {
            bf16x8 af[4], bfr[4];
#pragma unroll
            for (int mi = 0; mi < 4; ++mi) {
                int r = wr * 64 + mi * 16 + lrow;
                uint32_t off = (uint32_t)(r * 128 + ks * 64 + lkg * 16);
                af[mi] = *(const bf16x8*)(As + (off ^ ((r & 7) << 4)));
            }
#pragma unroll
            for (int ni = 0; ni < 4; ++ni) {
                int r = wc * 64 + ni * 16 + lrow;
                uint32_t off = (uint32_t)(r * 128 + ks * 64 + lkg * 16);
                bfr[ni] = *(const bf16x8*)(Bs + (off ^ ((r & 7) << 4)));
            }
#pragma unroll
            for (int mi = 0; mi < 4; ++mi)
#pragma unroll
                for (int ni = 0; ni < 4; ++ni)
                    acc[mi][ni] = __builtin_amdgcn_mfma_f32_16x16x32_bf16(
                        af[mi], bfr[ni], acc[mi][ni], 0, 0, 0);
        }
        __syncthreads();
    }
#pragma unroll
    for (int mi = 0; mi < 4; ++mi) {
#pragma unroll
        for (int ni = 0; ni < 4; ++ni) {
            int n = wc * 64 + ni * 16 + lrow;
            float bv = bias[n];
#pragma unroll
            for (int q = 0; q < 4; ++q) {
                float v = fmaxf(acc[mi][ni][q] + bv, 0.f);
                float vp = __shfl_xor(v, 1);
                int m = m0 + wr * 64 + mi * 16 + lkg * 4 + q;
                if (!(lane & 1) && m < M)
                    hb[(size_t)m * 64 + (n >> 1)] = pack2(v, vp);
            }
        }
    }
}

// ---------------- GEMM2 (MFMA bf16) + fused log_softmax ----------------
__global__ __launch_bounds__(256) void k_gemm2(const uint32_t* __restrict__ Abf,
                                               const float* __restrict__ W,
                                               const float* __restrict__ bias,
                                               float* __restrict__ out, int M) {
    __shared__ char As[128 * 128];
    __shared__ char Bs[64 * 128];
    __shared__ float redmax[2][128];
    __shared__ float redsum[2][128];
    const int tid = threadIdx.x;
    const int lane = tid & 63;
    const int wave = tid >> 6;
    const int wr = wave >> 1, wc = wave & 1;
    const int m0 = blockIdx.x * 128;
    const int lrow = lane & 15, lkg = lane >> 4;

    f32x4 acc[4][2];
#pragma unroll
    for (int mi = 0; mi < 4; ++mi)
#pragma unroll
        for (int ni = 0; ni < 2; ++ni) acc[mi][ni] = (f32x4){0.f, 0.f, 0.f, 0.f};

    for (int t = 0; t < 2; ++t) {
#pragma unroll
        for (int i = 0; i < 4; ++i) {
            int r = i * 32 + (tid >> 3);
            uint4 v = make_uint4(0u, 0u, 0u, 0u);
            if (m0 + r < M)
                v = *(const uint4*)&Abf[(size_t)(m0 + r) * 64 + t * 32 + (tid & 7) * 4];
            uint32_t off = (uint32_t)(r * 128 + (tid & 7) * 16);
            *(uint4*)(As + (off ^ ((r & 7) << 4))) = v;
        }
#pragma unroll
        for (int i = 0; i < 2; ++i) {
            int r = i * 32 + (tid >> 3);
            const float* p = &W[(size_t)r * 128 + t * 64 + (tid & 7) * 8];
            float4 v0 = *(const float4*)p, v1 = *(const float4*)(p + 4);
            uint4 pk = make_uint4(pack2(v0.x, v0.y), pack2(v0.z, v0.w),
                                  pack2(v1.x, v1.y), pack2(v1.z, v1.w));
            uint32_t off = (uint32_t)(r * 128 + (tid & 7) * 16);
            *(uint4*)(Bs + (off ^ ((r & 7) << 4))) = pk;
        }
        __syncthreads();
#pragma unroll
        for (int ks = 0; ks < 2; ++ks) {
            bf16x8 af[4], bfr[2];
#pragma unroll
            for (int mi = 0; mi < 4; ++mi) {
                int r = wr * 64 + mi * 16 + lrow;
                uint32_t off = (uint32_t)(r * 128 + ks * 64 + lkg * 16);
                af[mi] = *(const bf16x8*)(As + (off ^ ((r & 7) << 4)));
            }
#pragma unroll
            for (int ni = 0; ni < 2; ++ni) {
                int r = wc * 32 + ni * 16 + lrow;
                uint32_t off = (uint32_t)(r * 128 + ks * 64 + lkg * 16);
                bfr[ni] = *(const bf16x8*)(Bs + (off ^ ((r & 7) << 4)));
            }
#pragma unroll
            for (int mi = 0; mi < 4; ++mi)
#pragma unroll
                for (int ni = 0; ni < 2; ++ni)
                    acc[mi][ni] = __builtin_amdgcn_mfma_f32_16x16x32_bf16(
                        af[mi], bfr[ni], acc[mi][ni], 0, 0, 0);
        }
        __syncthreads();
    }

    float vb[4][2][4];
#pragma unroll
    for (int mi = 0; mi < 4; ++mi)
#pragma unroll
        for (int ni = 0; ni < 2; ++ni) {
            float bv = bias[wc * 32 + ni * 16 + lrow];
#pragma unroll
            for (int q = 0; q < 4; ++q) vb[mi][ni][q] = acc[mi][ni][q] + bv;
        }
#pragma unroll
    for (int mi = 0; mi < 4; ++mi)
#pragma unroll
        for (int q = 0; q < 4; ++q) {
            float mx = fmaxf(vb[mi][0][q], vb[mi][1][q]);
#pragma unroll
            for (int o = 1; o < 16; o <<= 1) mx = fmaxf(mx, __shfl_xor(mx, o));
            if (lrow == 0) redmax[wc][wr * 64 + mi * 16 + lkg * 4 + q] = mx;
        }
    __syncthreads();
    float fmv[4][4];
#pragma unroll
    for (int mi = 0; mi < 4; ++mi)
#pragma unroll
        for (int q = 0; q < 4; ++q) {
            int rl = wr * 64 + mi * 16 + lkg * 4 + q;
            float fm = fmaxf(redmax[0][rl], redmax[1][rl]);
            fmv[mi][q] = fm;
            float e = expf(vb[mi][0][q] - fm) + expf(vb[mi][1][q] - fm);
#pragma unroll
            for (int o = 1; o < 16; o <<= 1) e += __shfl_xor(e, o);
            if (lrow == 0) redsum[wc][rl] = e;
        }
    __syncthreads();
#pragma unroll
    for (int mi = 0; mi < 4; ++mi)
#pragma unroll
        for (int q = 0; q < 4; ++q) {
            int rl = wr * 64 + mi * 16 + lkg * 4 + q;
            int m = m0 + rl;
            if (m < M) {
                float ls = logf(redsum[0][rl] + redsum[1][rl]) + fmv[mi][q];
                out[(size_t)m * 64 + wc * 32 + lrow] = vb[mi][0][q] - ls;
                out[(size_t)m * 64 + wc * 32 + 16 + lrow] = vb[mi][1][q] - ls;
            }
        }
}

// ---------------- per-node gate scalars (layer 0 only; layer 1 fused into agg0) ----------
__global__ void k_ab(const uint32_t* __restrict__ hbv, const float* __restrict__ gw,
                     const float* __restrict__ gb, int layer,
                     const float* __restrict__ dinv,
                     float* __restrict__ av, float2* __restrict__ bd, int N) {
    int wid = threadIdx.x >> 6, lane = threadIdx.x & 63;
    int i = blockIdx.x * 4 + wid;
    if (i >= N) return;
    uint32_t u = hbv[(size_t)i * 64 + lane];
    float hx = bflo(u), hy = bfhi(u);
    float2 wi = *(const float2*)&gw[lane * 2];
    float2 wj = *(const float2*)&gw[128 + lane * 2];
    float pa = hx * wi.x + hy * wi.y;
    float pb = hx * wj.x + hy * wj.y;
    for (int o = 1; o < 64; o <<= 1) {
        pa += __shfl_xor(pa, o);
        pb += __shfl_xor(pb, o);
    }
    if (lane == 0) {
        av[i] = pa + gb[layer];
        bd[i] = make_float2(pb, dinv[i]);
    }
}

// ---------------- aggregation ----------------
// wave per node; neighbor lists are col-block sorted -> chip-wide L2-local sweep.
template <bool FUSE_AB, bool RAW_NT>
__global__ __launch_bounds__(256) void k_agg(const uint32_t* __restrict__ hb,
                                             const uint32_t* __restrict__ raw,
                                             const int* __restrict__ rp,
                                             const int* __restrict__ ecol,
                                             const float* __restrict__ av,
                                             const float2* __restrict__ bd,
                                             const float* __restrict__ dinv,
                                             uint32_t* __restrict__ hb_out,
                                             const float* __restrict__ gw_next,
                                             const float* __restrict__ gb_next,
                                             float* __restrict__ av_out,
                                             float2* __restrict__ bd_out, int N) {
    int wid = threadIdx.x >> 6, lane = threadIdx.x & 63;
    int i = blockIdx.x * 4 + wid;
    if (i >= N) return;
    int iu = __builtin_amdgcn_readfirstlane(i);
    int p0 = __builtin_amdgcn_readfirstlane(rp[iu]);
    int p1 = __builtin_amdgcn_readfirstlane(rp[iu + 1]);
    float a_i = av[iu];
    float di = dinv[iu];
    const int lg = lane >> 4;   // edge sub-slot
    const int ll = lane & 15;   // channel quad

    // issue raw-row load EARLY so its latency hides under the gather loop
    uint32_t r0 = 0, r1 = 0, r2 = 0, r3 = 0;
    if (lane < 16) {
        const uint32_t* rpt = raw + (size_t)i * 64 + ll * 4;
        if (RAW_NT) {
            r0 = __builtin_nontemporal_load(rpt + 0);
            r1 = __builtin_nontemporal_load(rpt + 1);
            r2 = __builtin_nontemporal_load(rpt + 2);
            r3 = __builtin_nontemporal_load(rpt + 3);
        } else {
            r0 = rpt[0]; r1 = rpt[1]; r2 = rpt[2]; r3 = rpt[3];
        }
    }

    float acc[8];
#pragma unroll
    for (int j = 0; j < 8; ++j) acc[j] = 0.f;

    for (int b0 = p0; b0 < p1; b0 += 64) {
        int cnt = min(64, p1 - b0);
        // Phase A: vector weight compute for this batch
        uint32_t wcp = 0u;
        if (lane < cnt) {
            int c = __builtin_nontemporal_load(&ecol[b0 + lane]);
            float2 t = bd[c];
            float w = fast_tanh(a_i + t.x) * t.y;
            wcp = (f2bf(w) << 16) | (uint32_t)c;
        }
        // Phase B: 8 edges per iteration (2 gathers in flight per lane)
        int k = 0;
        for (; k + 8 <= cnt; k += 8) {
            uint32_t wx0 = __builtin_amdgcn_ds_bpermute((k + lg) << 2, (int)wcp);
            uint32_t wx1 = __builtin_amdgcn_ds_bpermute((k + 4 + lg) << 2, (int)wcp);
            float w0 = bfhi(wx0);
            float w1 = bfhi(wx1);
            int c0 = (int)(wx0 & 0xffffu);
            int c1 = (int)(wx1 & 0xffffu);
            uint4 u0 = *((const uint4*)(hb + ((size_t)c0 << 6)) + ll);
            uint4 u1 = *((const uint4*)(hb + ((size_t)c1 << 6)) + ll);
            acc[0] = fmaf(w0, bflo(u0.x), acc[0]); acc[1] = fmaf(w0, bfhi(u0.x), acc[1]);
            acc[2] = fmaf(w0, bflo(u0.y), acc[2]); acc[3] = fmaf(w0, bfhi(u0.y), acc[3]);
            acc[4] = fmaf(w0, bflo(u0.z), acc[4]); acc[5] = fmaf(w0, bfhi(u0.z), acc[5]);
            acc[6] = fmaf(w0, bflo(u0.w), acc[6]); acc[7] = fmaf(w0, bfhi(u0.w), acc[7]);
            acc[0] = fmaf(w1, bflo(u1.x), acc[0]); acc[1] = fmaf(w1, bfhi(u1.x), acc[1]);
            acc[2] = fmaf(w1, bflo(u1.y), acc[2]); acc[3] = fmaf(w1, bfhi(u1.y), acc[3]);
            acc[4] = fmaf(w1, bflo(u1.z), acc[4]); acc[5] = fmaf(w1, bfhi(u1.z), acc[5]);
            acc[6] = fmaf(w1, bflo(u1.w), acc[6]); acc[7] = fmaf(w1, bfhi(u1.w), acc[7]);
        }
        for (; k < cnt; k += 4) {
            uint32_t wx = __builtin_amdgcn_ds_bpermute((k + lg) << 2, (int)wcp);
            float w = bfhi(wx);           // 0 for out-of-range slots
            int c = (int)(wx & 0xffffu);
            uint4 u = *((const uint4*)(hb + ((size_t)c << 6)) + ll);
            acc[0] = fmaf(w, bflo(u.x), acc[0]); acc[1] = fmaf(w, bfhi(u.x), acc[1]);
            acc[2] = fmaf(w, bflo(u.y), acc[2]); acc[3] = fmaf(w, bfhi(u.y), acc[3]);
            acc[4] = fmaf(w, bflo(u.z), acc[4]); acc[5] = fmaf(w, bfhi(u.z), acc[5]);
            acc[6] = fmaf(w, bflo(u.w), acc[6]); acc[7] = fmaf(w, bfhi(u.w), acc[7]);
        }
    }
    // Phase C: reduce across the 4 edge sub-slots
#pragma unroll
    for (int j = 0; j < 8; ++j) {
        acc[j] += __shfl_xor(acc[j], 16);
        acc[j] += __shfl_xor(acc[j], 32);
    }
    // Phase D (+E): lanes 0-15 own 8 channels each
    if (lane < 16) {
        float o[8];
        o[0] = EPSF * bflo(r0) + di * acc[0]; o[1] = EPSF * bfhi(r0) + di * acc[1];
        o[2] = EPSF * bflo(r1) + di * acc[2]; o[3] = EPSF * bfhi(r1) + di * acc[3];
        o[4] = EPSF * bflo(r2) + di * acc[4]; o[5] = EPSF * bfhi(r2) + di * acc[5];
        o[6] = EPSF * bflo(r3) + di * acc[6]; o[7] = EPSF * bfhi(r3) + di * acc[7];
        uint4 w4;
        w4.x = pack2(o[0], o[1]); w4.y = pack2(o[2], o[3]);
        w4.z = pack2(o[4], o[5]); w4.w = pack2(o[6], o[7]);
        *((uint4*)(hb_out + (size_t)i * 64) + ll) = w4;
        if (FUSE_AB) {
            float pa = 0.f, pb = 0.f;
#pragma unroll
            for (int j = 0; j < 8; ++j) {
                int ch = ll * 8 + j;
                pa = fmaf(o[j], gw_next[ch], pa);
                pb = fmaf(o[j], gw_next[128 + ch], pb);
            }
#pragma unroll
            for (int off = 1; off < 16; off <<= 1) {
                pa += __shfl_xor(pa, off);
                pb += __shfl_xor(pb, off);
            }
            if (ll == 0) {
                av_out[i] = pa + gb_next[0];
                bd_out[i] = make_float2(pb, di);
            }
        }
    }
}

extern "C" void kernel_launch(void* const* d_in, const int* in_sizes, int n_in,
                              void* d_out, int out_size, void* d_ws, size_t ws_size,
                              hipStream_t stream) {
    const float* x = (const float*)d_in[0];
    const int* ei = (const int*)d_in[1];
    const float* t1w = (const float*)d_in[2];
    const float* t1b = (const float*)d_in[3];
    const float* gw = (const float*)d_in[4];
    const float* gb = (const float*)d_in[5];
    const float* t2w = (const float*)d_in[6];
    const float* t2b = (const float*)d_in[7];
    float* out = (float*)d_out;

    const int INC = 256;
    const int N = in_sizes[0] / INC;
    const int E = in_sizes[1] / 2;
    const int NB = (N + NPB - 1) >> SHB;
    const int NCB = ((N - 1) >> CBSH) + 1;
    const int nkeys = NB * NCB;
    const int nblk = (E + CHUNK - 1) / CHUNK;

    char* ws = (char*)d_ws;
    auto alloc = [&](size_t bytes) {
        char* p = ws;
        ws += (bytes + 255) & ~(size_t)255;
        return p;
    };
    int* hist = (int*)alloc((size_t)nkeys * nblk * 4);
    int* btot = (int*)alloc((size_t)nkeys * 4);
    int* bbase = (int*)alloc((size_t)(nkeys + 1) * 4);
    uint32_t* ebuf = (uint32_t*)alloc((size_t)E * 4);
    int* rp = (int*)alloc((size_t)(N + 1) * 4);
    float* dinv = (float*)alloc((size_t)N * 4);
    int* ecol = (int*)alloc((size_t)E * 4);
    float* av0 = (float*)alloc((size_t)N * 4);
    float* av1 = (float*)alloc((size_t)N * 4);
    float2* bd0 = (float2*)alloc((size_t)N * 8);
    float2* bd1 = (float2*)alloc((size_t)N * 8);
    uint32_t* hb0 = (uint32_t*)alloc((size_t)N * 64 * 4);
    uint32_t* hb1 = (uint32_t*)alloc((size_t)N * 64 * 4);
    uint32_t* hb2 = (uint32_t*)alloc((size_t)N * 64 * 4);

    // ---- CSR build, keys = (rowbucket, colblock) -> col-sweep locality ----
    k_hist<<<nblk, 256, 0, stream>>>(ei, E, hist, nkeys, NCB);
    k_scanA<<<(nkeys + 63) / 64, 64, 0, stream>>>(hist, nblk, nkeys, btot);
    k_scanB<<<1, 256, 0, stream>>>(btot, nkeys, bbase);
    k_binwrite<<<nblk, 256, 0, stream>>>(ei, E, hist, bbase, ebuf, nkeys, NCB);
    k_csr<<<NB, 256, 0, stream>>>(ebuf, bbase, rp, dinv, ecol, N, E, NB, NCB);

    // ---- hb0 = relu(x @ t1_w^T + t1_b) (bf16, MFMA) ----
    k_gemm1<<<(N + 127) / 128, 256, 0, stream>>>(x, t1w, t1b, hb0, N);

    // ---- layer 0 gate scalars ----
    k_ab<<<(N + 3) / 4, 256, 0, stream>>>(hb0, gw + 0 * 256, gb, 0, dinv, av0, bd0, N);
    // ---- layer 0: hb0 -> hb1, fused layer-1 ab ----
    k_agg<true, false><<<(N + 3) / 4, 256, 0, stream>>>(
        hb0, hb0, rp, ecol, av0, bd0, dinv, hb1, gw + 1 * 256, gb + 1, av1, bd1, N);
    // ---- layer 1: hb1 -> hb2 (raw = hb0, nontemporal) ----
    k_agg<false, true><<<(N + 3) / 4, 256, 0, stream>>>(
        hb1, hb0, rp, ecol, av1, bd1, dinv, hb2, nullptr, nullptr, nullptr, nullptr, N);

    // ---- out = log_softmax(hb2 @ t2_w^T + t2_b) (MFMA, fused) ----
    k_gemm2<<<(N + 127) / 128, 256, 0, stream>>>(hb2, t2w, t2b, out, N);
}

// Round 9
// 200.536 us; speedup vs baseline: 1.5614x; 1.5614x over previous
//
#include <hip/hip_runtime.h>
#include <math.h>

#define EPSF 0.3f
#define NPB 128      // nodes per row-bucket
#define SHB 7        // log2(NPB)
#define MAXNB 512    // max buckets (N <= 65536; also packed-edge limit N < 65536)
#define CHUNK 4096   // edges per block in pack/binwrite
#define MAXSEG 8192  // LDS-staged edges per bucket in k_csr (avg ~4090)

typedef __attribute__((ext_vector_type(8))) short bf16x8;
typedef __attribute__((ext_vector_type(4))) float f32x4;

// ---------------- bf16 helpers ----------------
__device__ __forceinline__ uint32_t f2bf(float f) {
    uint32_t u = __float_as_uint(f);
    return (u + 0x7fffu + ((u >> 16) & 1u)) >> 16;  // RNE
}
__device__ __forceinline__ uint32_t pack2(float lo, float hi) {
    return f2bf(lo) | (f2bf(hi) << 16);
}
__device__ __forceinline__ float bflo(uint32_t u) { return __uint_as_float(u << 16); }
__device__ __forceinline__ float bfhi(uint32_t u) { return __uint_as_float(u & 0xffff0000u); }

// fast tanh: 1 - 2/(e^{2x}+1); v_exp-based, |err| ~1e-6, saturates correctly
__device__ __forceinline__ float fast_tanh(float x) {
    float e = __expf(2.f * x);
    return 1.f - 2.f * __builtin_amdgcn_rcpf(e + 1.f);
}

__device__ __forceinline__ int edge_at(const int* ei, int is64, size_t idx) {
    if (is64) return (int)((const long long*)ei)[idx];
    return ei[idx];
}

// per-block int32/int64 detection: sample odd dwords of this block's row slice
__device__ __forceinline__ int detect_is64(const int* ei, int base, int E) {
    __shared__ int s_nz;
    if (threadIdx.x == 0) s_nz = 0;
    __syncthreads();
    int lim = min(512, E - base);
    int nz = 0;
    for (int t = threadIdx.x; t < lim; t += 256)
        nz |= (ei[2 * (size_t)(base + t) + 1] != 0);
    if (nz) atomicOr(&s_nz, 1);
    __syncthreads();
    return s_nz == 0;
}

// ---------------- pack + bucket histogram: pk[e]=(r<<16)|c, hist[bucket][blk] ------------
__global__ __launch_bounds__(256) void k_pack(const int* __restrict__ ei, int E,
                                              uint32_t* __restrict__ pk,
                                              int* __restrict__ hist, int nblk, int NB) {
    __shared__ int lh[MAXNB];
    int base = blockIdx.x * CHUNK;
    int is64 = detect_is64(ei, base, E);
    for (int b = threadIdx.x; b < NB; b += 256) lh[b] = 0;
    __syncthreads();
    for (int j = threadIdx.x; j < CHUNK; j += 256) {
        int e = base + j;
        if (e < E) {
            int r = edge_at(ei, is64, e);
            int c = edge_at(ei, is64, (size_t)E + e);
            pk[e] = ((uint32_t)r << 16) | (uint32_t)c;
            atomicAdd(&lh[r >> SHB], 1);
        }
    }
    __syncthreads();
    for (int b = threadIdx.x; b < NB; b += 256)
        hist[(size_t)b * nblk + blockIdx.x] = lh[b];
}

// per-bucket exclusive scan across blocks (wave scan, coalesced)
__global__ void k_scanA(int* __restrict__ hist, int nblk, int* __restrict__ btot) {
    int b = blockIdx.x;
    int lane = threadIdx.x;
    int run = 0;
    for (int seg = 0; seg < nblk; seg += 64) {
        int idx = seg + lane;
        int v = (idx < nblk) ? hist[(size_t)b * nblk + idx] : 0;
        int s = v;
        for (int o = 1; o < 64; o <<= 1) {
            int t = __shfl_up(s, o);
            if (lane >= o) s += t;
        }
        if (idx < nblk) hist[(size_t)b * nblk + idx] = run + s - v;
        run += __shfl(s, 63);
    }
    if (lane == 0) btot[b] = run;
}

// exclusive scan over bucket totals -> bbase[0..NB]
__global__ void k_scanB(const int* __restrict__ btot, int NB, int* __restrict__ bbase) {
    __shared__ int s[MAXNB];
    int t = threadIdx.x;
    int v = (t < NB) ? btot[t] : 0;
    s[t] = v;
    __syncthreads();
    for (int o = 1; o < MAXNB; o <<= 1) {
        int x = (t >= o) ? s[t - o] : 0;
        __syncthreads();
        s[t] += x;
        __syncthreads();
    }
    if (t < NB) bbase[t] = s[t] - v;
    if (t == MAXNB - 1) bbase[NB] = s[t];
}

// scatter packed edges into bucket-ordered ebuf (entries stay (r<<16)|c)
__global__ __launch_bounds__(256) void k_binwrite(const uint32_t* __restrict__ pk, int E,
                                                  const int* __restrict__ hist,
                                                  const int* __restrict__ bbase,
                                                  uint32_t* __restrict__ ebuf,
                                                  int nblk, int NB) {
    __shared__ int lcnt[MAXNB];
    int base = blockIdx.x * CHUNK;
    for (int b = threadIdx.x; b < NB; b += 256)
        lcnt[b] = bbase[b] + hist[(size_t)b * nblk + blockIdx.x];
    __syncthreads();
    for (int j = threadIdx.x; j < CHUNK; j += 256) {
        int e = base + j;
        if (e < E) {
            uint32_t v = __builtin_nontemporal_load(&pk[e]);
            int pos = atomicAdd(&lcnt[v >> (16 + SHB)], 1);
            ebuf[pos] = v;
        }
    }
}

// one block per bucket: LDS-staged count -> rp/dinv -> scatter -> ecol
__global__ __launch_bounds__(256) void k_csr(const uint32_t* __restrict__ ebuf,
                                             const int* __restrict__ bbase,
                                             int* __restrict__ rp, float* __restrict__ dinv,
                                             int* __restrict__ ecol, int N, int E, int NB) {
    __shared__ uint32_t seg[MAXSEG];
    __shared__ int cnt[NPB];
    __shared__ int sc[NPB];
    __shared__ int cur[NPB];
    int b = blockIdx.x;
    int tid = threadIdx.x;
    int p0 = bbase[b], p1 = bbase[b + 1];
    int len = p1 - p0;
    bool fits = (len <= MAXSEG);
    int n0 = b << SHB;
    if (tid < NPB) cnt[tid] = 0;
    __syncthreads();
    if (fits) {
        for (int j = tid; j < len; j += 256) {
            uint32_t v = ebuf[p0 + j];
            seg[j] = v;
            atomicAdd(&cnt[(v >> 16) & (NPB - 1)], 1);
        }
    } else {
        for (int j = tid; j < len; j += 256)
            atomicAdd(&cnt[(ebuf[p0 + j] >> 16) & (NPB - 1)], 1);
    }
    __syncthreads();
    if (tid < NPB) sc[tid] = cnt[tid];
    __syncthreads();
    for (int o = 1; o < NPB; o <<= 1) {
        int v = (tid < NPB && tid >= o) ? sc[tid - o] : 0;
        __syncthreads();
        if (tid < NPB) sc[tid] += v;
        __syncthreads();
    }
    if (tid < NPB) {
        int off = sc[tid] - cnt[tid];
        cur[tid] = off;
        int node = n0 + tid;
        if (node < N) {
            rp[node] = p0 + off;
            int d = cnt[tid];
            dinv[node] = d > 0 ? rsqrtf((float)d) : 0.f;
        }
    }
    if (b == NB - 1 && tid == 0) rp[N] = E;
    __syncthreads();
    if (fits) {
        for (int j = tid; j < len; j += 256) {
            uint32_t v = seg[j];
            int pos = p0 + atomicAdd(&cur[(v >> 16) & (NPB - 1)], 1);
            ecol[pos] = (int)(v & 0xffffu);
        }
    } else {
        for (int j = tid; j < len; j += 256) {
            uint32_t v = ebuf[p0 + j];
            int pos = p0 + atomicAdd(&cur[(v >> 16) & (NPB - 1)], 1);
            ecol[pos] = (int)(v & 0xffffu);
        }
    }
}

// ---------------- GEMM1 (MFMA bf16): hb = relu(x @ t1_w^T + b) as bf16 ----------------
__global__ __launch_bounds__(256) void k_gemm1(const float* __restrict__ A,
                                               const float* __restrict__ W,
                                               const float* __restrict__ bias,
                                               uint32_t* __restrict__ hb, int M) {
    __shared__ char As[128 * 128];
    __shared__ char Bs[128 * 128];
    const int tid = threadIdx.x;
    const int lane = tid & 63;
    const int wave = tid >> 6;
    const int wr = wave >> 1, wc = wave & 1;
    const int m0 = blockIdx.x * 128;
    const int lrow = lane & 15, lkg = lane >> 4;
    const int sr = tid >> 3;
    const int sc = (tid & 7) * 8;

    f32x4 acc[4][4];
#pragma unroll
    for (int mi = 0; mi < 4; ++mi)
#pragma unroll
        for (int ni = 0; ni < 4; ++ni) acc[mi][ni] = (f32x4){0.f, 0.f, 0.f, 0.f};

    for (int t = 0; t < 4; ++t) {
        const int k0 = t * 64;
#pragma unroll
        for (int i = 0; i < 4; ++i) {
            int r = i * 32 + sr;
            float4 v0 = make_float4(0.f, 0.f, 0.f, 0.f), v1 = v0;
            if (m0 + r < M) {
                const float* p = &A[(size_t)(m0 + r) * 256 + k0 + sc];
                v0 = *(const float4*)p;
                v1 = *(const float4*)(p + 4);
            }
            uint4 pk = make_uint4(pack2(v0.x, v0.y), pack2(v0.z, v0.w),
                                  pack2(v1.x, v1.y), pack2(v1.z, v1.w));
            uint32_t off = (uint32_t)(r * 128 + sc * 2);
            *(uint4*)(As + (off ^ ((r & 7) << 4))) = pk;
        }
#pragma unroll
        for (int i = 0; i < 4; ++i) {
            int r = i * 32 + sr;
            const float* p = &W[(size_t)r * 256 + k0 + sc];
            float4 v0 = *(const float4*)p;
            float4 v1 = *(const float4*)(p + 4);
            uint4 pk = make_uint4(pack2(v0.x, v0.y), pack2(v0.z, v0.w),
                                  pack2(v1.x, v1.y), pack2(v1.z, v1.w));
            uint32_t off = (uint32_t)(r * 128 + sc * 2);
            *(uint4*)(Bs + (off ^ ((r & 7) << 4))) = pk;
        }
        __syncthreads();
#pragma unroll
        for (int ks = 0; ks < 2; ++ks) {
            bf16x8 af[4], bfr[4];
#pragma unroll
            for (int mi = 0; mi < 4; ++mi) {
                int r = wr * 64 + mi * 16 + lrow;
                uint32_t off = (uint32_t)(r * 128 + ks * 64 + lkg * 16);
                af[mi] = *(const bf16x8*)(As + (off ^ ((r & 7) << 4)));
            }
#pragma unroll
            for (int ni = 0; ni < 4; ++ni) {
                int r = wc * 64 + ni * 16 + lrow;
                uint32_t off = (uint32_t)(r * 128 + ks * 64 + lkg * 16);
                bfr[ni] = *(const bf16x8*)(Bs + (off ^ ((r & 7) << 4)));
            }
#pragma unroll
            for (int mi = 0; mi < 4; ++mi)
#pragma unroll
                for (int ni = 0; ni < 4; ++ni)
                    acc[mi][ni] = __builtin_amdgcn_mfma_f32_16x16x32_bf16(
                        af[mi], bfr[ni], acc[mi][ni], 0, 0, 0);
        }
        __syncthreads();
    }
#pragma unroll
    for (int mi = 0; mi < 4; ++mi) {
#pragma unroll
        for (int ni = 0; ni < 4; ++ni) {
            int n = wc * 64 + ni * 16 + lrow;
            float bv = bias[n];
#pragma unroll
            for (int q = 0; q < 4; ++q) {
                float v = fmaxf(acc[mi][ni][q] + bv, 0.f);
                float vp = __shfl_xor(v, 1);
                int m = m0 + wr * 64 + mi * 16 + lkg * 4 + q;
                if (!(lane & 1) && m < M)
                    hb[(size_t)m * 64 + (n >> 1)] = pack2(v, vp);
            }
        }
    }
}

// ---------------- GEMM2 (MFMA bf16) + fused log_softmax ----------------
__global__ __launch_bounds__(256) void k_gemm2(const uint32_t* __restrict__ Abf,
                                               const float* __restrict__ W,
                                               const float* __restrict__ bias,
                                               float* __restrict__ out, int M) {
    __shared__ char As[128 * 128];
    __shared__ char Bs[64 * 128];
    __shared__ float redmax[2][128];
    __shared__ float redsum[2][128];
    const int tid = threadIdx.x;
    const int lane = tid & 63;
    const int wave = tid >> 6;
    const int wr = wave >> 1, wc = wave & 1;
    const int m0 = blockIdx.x * 128;
    const int lrow = lane & 15, lkg = lane >> 4;

    f32x4 acc[4][2];
#pragma unroll
    for (int mi = 0; mi < 4; ++mi)
#pragma unroll
        for (int ni = 0; ni < 2; ++ni) acc[mi][ni] = (f32x4){0.f, 0.f, 0.f, 0.f};

    for (int t = 0; t < 2; ++t) {
#pragma unroll
        for (int i = 0; i < 4; ++i) {
            int r = i * 32 + (tid >> 3);
            uint4 v = make_uint4(0u, 0u, 0u, 0u);
            if (m0 + r < M)
                v = *(const uint4*)&Abf[(size_t)(m0 + r) * 64 + t * 32 + (tid & 7) * 4];
            uint32_t off = (uint32_t)(r * 128 + (tid & 7) * 16);
            *(uint4*)(As + (off ^ ((r & 7) << 4))) = v;
        }
#pragma unroll
        for (int i = 0; i < 2; ++i) {
            int r = i * 32 + (tid >> 3);
            const float* p = &W[(size_t)r * 128 + t * 64 + (tid & 7) * 8];
            float4 v0 = *(const float4*)p, v1 = *(const float4*)(p + 4);
            uint4 pk = make_uint4(pack2(v0.x, v0.y), pack2(v0.z, v0.w),
                                  pack2(v1.x, v1.y), pack2(v1.z, v1.w));
            uint32_t off = (uint32_t)(r * 128 + (tid & 7) * 16);
            *(uint4*)(Bs + (off ^ ((r & 7) << 4))) = pk;
        }
        __syncthreads();
#pragma unroll
        for (int ks = 0; ks < 2; ++ks) {
            bf16x8 af[4], bfr[2];
#pragma unroll
            for (int mi = 0; mi < 4; ++mi) {
                int r = wr * 64 + mi * 16 + lrow;
                uint32_t off = (uint32_t)(r * 128 + ks * 64 + lkg * 16);
                af[mi] = *(const bf16x8*)(As + (off ^ ((r & 7) << 4)));
            }
#pragma unroll
            for (int ni = 0; ni < 2; ++ni) {
                int r = wc * 32 + ni * 16 + lrow;
                uint32_t off = (uint32_t)(r * 128 + ks * 64 + lkg * 16);
                bfr[ni] = *(const bf16x8*)(Bs + (off ^ ((r & 7) << 4)));
            }
#pragma unroll
            for (int mi = 0; mi < 4; ++mi)
#pragma unroll
                for (int ni = 0; ni < 2; ++ni)
                    acc[mi][ni] = __builtin_amdgcn_mfma_f32_16x16x32_bf16(
                        af[mi], bfr[ni], acc[mi][ni], 0, 0, 0);
        }
        __syncthreads();
    }

    float vb[4][2][4];
#pragma unroll
    for (int mi = 0; mi < 4; ++mi)
#pragma unroll
        for (int ni = 0; ni < 2; ++ni) {
            float bv = bias[wc * 32 + ni * 16 + lrow];
#pragma unroll
            for (int q = 0; q < 4; ++q) vb[mi][ni][q] = acc[mi][ni][q] + bv;
        }
#pragma unroll
    for (int mi = 0; mi < 4; ++mi)
#pragma unroll
        for (int q = 0; q < 4; ++q) {
            float mx = fmaxf(vb[mi][0][q], vb[mi][1][q]);
#pragma unroll
            for (int o = 1; o < 16; o <<= 1) mx = fmaxf(mx, __shfl_xor(mx, o));
            if (lrow == 0) redmax[wc][wr * 64 + mi * 16 + lkg * 4 + q] = mx;
        }
    __syncthreads();
    float fmv[4][4];
#pragma unroll
    for (int mi = 0; mi < 4; ++mi)
#pragma unroll
        for (int q = 0; q < 4; ++q) {
            int rl = wr * 64 + mi * 16 + lkg * 4 + q;
            float fm = fmaxf(redmax[0][rl], redmax[1][rl]);
            fmv[mi][q] = fm;
            float e = expf(vb[mi][0][q] - fm) + expf(vb[mi][1][q] - fm);
#pragma unroll
            for (int o = 1; o < 16; o <<= 1) e += __shfl_xor(e, o);
            if (lrow == 0) redsum[wc][rl] = e;
        }
    __syncthreads();
#pragma unroll
    for (int mi = 0; mi < 4; ++mi)
#pragma unroll
        for (int q = 0; q < 4; ++q) {
            int rl = wr * 64 + mi * 16 + lkg * 4 + q;
            int m = m0 + rl;
            if (m < M) {
                float ls = logf(redsum[0][rl] + redsum[1][rl]) + fmv[mi][q];
                out[(size_t)m * 64 + wc * 32 + lrow] = vb[mi][0][q] - ls;
                out[(size_t)m * 64 + wc * 32 + 16 + lrow] = vb[mi][1][q] - ls;
            }
        }
}

// ---------------- per-node gate scalars (layer 0 only; layer 1 fused into agg0) ----------
__global__ void k_ab(const uint32_t* __restrict__ hbv, const float* __restrict__ gw,
                     const float* __restrict__ gb, int layer,
                     const float* __restrict__ dinv,
                     float* __restrict__ av, float2* __restrict__ bd, int N) {
    int wid = threadIdx.x >> 6, lane = threadIdx.x & 63;
    int i = blockIdx.x * 4 + wid;
    if (i >= N) return;
    uint32_t u = hbv[(size_t)i * 64 + lane];
    float hx = bflo(u), hy = bfhi(u);
    float2 wi = *(const float2*)&gw[lane * 2];
    float2 wj = *(const float2*)&gw[128 + lane * 2];
    float pa = hx * wi.x + hy * wi.y;
    float pb = hx * wj.x + hy * wj.y;
    for (int o = 1; o < 64; o <<= 1) {
        pa += __shfl_xor(pa, o);
        pb += __shfl_xor(pb, o);
    }
    if (lane == 0) {
        av[i] = pa + gb[layer];
        bd[i] = make_float2(pb, dinv[i]);
    }
}

// ---------------- aggregation ----------------
// wave per node. Phase A: vector weight compute, pack (w_bf16<<16 | c).
// Phase B: 8 edges/iter (2 independent gathers in flight per lane).
// Phase C: cross-group reduce. Phase D: write (lanes 0-15, uint4).
// Phase E (FUSE_AB): compute next layer's av/bd from the output row.
template <bool FUSE_AB, bool RAW_NT>
__global__ __launch_bounds__(256) void k_agg(const uint32_t* __restrict__ hb,
                                             const uint32_t* __restrict__ raw,
                                             const int* __restrict__ rp,
                                             const int* __restrict__ ecol,
                                             const float* __restrict__ av,
                                             const float2* __restrict__ bd,
                                             const float* __restrict__ dinv,
                                             uint32_t* __restrict__ hb_out,
                                             const float* __restrict__ gw_next,
                                             const float* __restrict__ gb_next,
                                             float* __restrict__ av_out,
                                             float2* __restrict__ bd_out, int N) {
    int wid = threadIdx.x >> 6, lane = threadIdx.x & 63;
    int i = blockIdx.x * 4 + wid;
    if (i >= N) return;
    int iu = __builtin_amdgcn_readfirstlane(i);
    int p0 = __builtin_amdgcn_readfirstlane(rp[iu]);
    int p1 = __builtin_amdgcn_readfirstlane(rp[iu + 1]);
    float a_i = av[iu];
    float di = dinv[iu];
    const int lg = lane >> 4;   // edge sub-slot
    const int ll = lane & 15;   // channel quad

    // issue raw-row load EARLY so its latency hides under the gather loop
    uint32_t r0 = 0, r1 = 0, r2 = 0, r3 = 0;
    if (lane < 16) {
        const uint32_t* rpt = raw + (size_t)i * 64 + ll * 4;
        if (RAW_NT) {
            r0 = __builtin_nontemporal_load(rpt + 0);
            r1 = __builtin_nontemporal_load(rpt + 1);
            r2 = __builtin_nontemporal_load(rpt + 2);
            r3 = __builtin_nontemporal_load(rpt + 3);
        } else {
            r0 = rpt[0]; r1 = rpt[1]; r2 = rpt[2]; r3 = rpt[3];
        }
    }

    float acc[8];
#pragma unroll
    for (int j = 0; j < 8; ++j) acc[j] = 0.f;

    for (int b0 = p0; b0 < p1; b0 += 64) {
        int cnt = min(64, p1 - b0);
        // Phase A: vector weight compute for this batch
        uint32_t wcp = 0u;
        if (lane < cnt) {
            int c = __builtin_nontemporal_load(&ecol[b0 + lane]);
            float2 t = bd[c];
            float w = fast_tanh(a_i + t.x) * t.y;
            wcp = (f2bf(w) << 16) | (uint32_t)c;
        }
        // Phase B: 8 edges per iteration (2 gathers in flight per lane)
        int k = 0;
        for (; k + 8 <= cnt; k += 8) {
            uint32_t wx0 = __builtin_amdgcn_ds_bpermute((k + lg) << 2, (int)wcp);
            uint32_t wx1 = __builtin_amdgcn_ds_bpermute((k + 4 + lg) << 2, (int)wcp);
            float w0 = bfhi(wx0);
            float w1 = bfhi(wx1);
            int c0 = (int)(wx0 & 0xffffu);
            int c1 = (int)(wx1 & 0xffffu);
            uint4 u0 = *((const uint4*)(hb + ((size_t)c0 << 6)) + ll);
            uint4 u1 = *((const uint4*)(hb + ((size_t)c1 << 6)) + ll);
            acc[0] = fmaf(w0, bflo(u0.x), acc[0]); acc[1] = fmaf(w0, bfhi(u0.x), acc[1]);
            acc[2] = fmaf(w0, bflo(u0.y), acc[2]); acc[3] = fmaf(w0, bfhi(u0.y), acc[3]);
            acc[4] = fmaf(w0, bflo(u0.z), acc[4]); acc[5] = fmaf(w0, bfhi(u0.z), acc[5]);
            acc[6] = fmaf(w0, bflo(u0.w), acc[6]); acc[7] = fmaf(w0, bfhi(u0.w), acc[7]);
            acc[0] = fmaf(w1, bflo(u1.x), acc[0]); acc[1] = fmaf(w1, bfhi(u1.x), acc[1]);
            acc[2] = fmaf(w1, bflo(u1.y), acc[2]); acc[3] = fmaf(w1, bfhi(u1.y), acc[3]);
            acc[4] = fmaf(w1, bflo(u1.z), acc[4]); acc[5] = fmaf(w1, bfhi(u1.z), acc[5]);
            acc[6] = fmaf(w1, bflo(u1.w), acc[6]); acc[7] = fmaf(w1, bfhi(u1.w), acc[7]);
        }
        for (; k < cnt; k += 4) {
            uint32_t wx = __builtin_amdgcn_ds_bpermute((k + lg) << 2, (int)wcp);
            float w = bfhi(wx);           // 0 for out-of-range slots
            int c = (int)(wx & 0xffffu);
            uint4 u = *((const uint4*)(hb + ((size_t)c << 6)) + ll);
            acc[0] = fmaf(w, bflo(u.x), acc[0]); acc[1] = fmaf(w, bfhi(u.x), acc[1]);
            acc[2] = fmaf(w, bflo(u.y), acc[2]); acc[3] = fmaf(w, bfhi(u.y), acc[3]);
            acc[4] = fmaf(w, bflo(u.z), acc[4]); acc[5] = fmaf(w, bfhi(u.z), acc[5]);
            acc[6] = fmaf(w, bflo(u.w), acc[6]); acc[7] = fmaf(w, bfhi(u.w), acc[7]);
        }
    }
    // Phase C: reduce across the 4 edge sub-slots
#pragma unroll
    for (int j = 0; j < 8; ++j) {
        acc[j] += __shfl_xor(acc[j], 16);
        acc[j] += __shfl_xor(acc[j], 32);
    }
    // Phase D (+E): lanes 0-15 own 8 channels each
    if (lane < 16) {
        float o[8];
        o[0] = EPSF * bflo(r0) + di * acc[0]; o[1] = EPSF * bfhi(r0) + di * acc[1];
        o[2] = EPSF * bflo(r1) + di * acc[2]; o[3] = EPSF * bfhi(r1) + di * acc[3];
        o[4] = EPSF * bflo(r2) + di * acc[4]; o[5] = EPSF * bfhi(r2) + di * acc[5];
        o[6] = EPSF * bflo(r3) + di * acc[6]; o[7] = EPSF * bfhi(r3) + di * acc[7];
        uint4 w4;
        w4.x = pack2(o[0], o[1]); w4.y = pack2(o[2], o[3]);
        w4.z = pack2(o[4], o[5]); w4.w = pack2(o[6], o[7]);
        *((uint4*)(hb_out + (size_t)i * 64) + ll) = w4;
        if (FUSE_AB) {
            float pa = 0.f, pb = 0.f;
#pragma unroll
            for (int j = 0; j < 8; ++j) {
                int ch = ll * 8 + j;
                pa = fmaf(o[j], gw_next[ch], pa);
                pb = fmaf(o[j], gw_next[128 + ch], pb);
            }
#pragma unroll
            for (int off = 1; off < 16; off <<= 1) {
                pa += __shfl_xor(pa, off);
                pb += __shfl_xor(pb, off);
            }
            if (ll == 0) {
                av_out[i] = pa + gb_next[0];
                bd_out[i] = make_float2(pb, di);
            }
        }
    }
}

extern "C" void kernel_launch(void* const* d_in, const int* in_sizes, int n_in,
                              void* d_out, int out_size, void* d_ws, size_t ws_size,
                              hipStream_t stream) {
    const float* x = (const float*)d_in[0];
    const int* ei = (const int*)d_in[1];
    const float* t1w = (const float*)d_in[2];
    const float* t1b = (const float*)d_in[3];
    const float* gw = (const float*)d_in[4];
    const float* gb = (const float*)d_in[5];
    const float* t2w = (const float*)d_in[6];
    const float* t2b = (const float*)d_in[7];
    float* out = (float*)d_out;

    const int INC = 256;
    const int N = in_sizes[0] / INC;
    const int E = in_sizes[1] / 2;
    const int NB = (N + NPB - 1) >> SHB;
    const int nblk = (E + CHUNK - 1) / CHUNK;

    char* ws = (char*)d_ws;
    auto alloc = [&](size_t bytes) {
        char* p = ws;
        ws += (bytes + 255) & ~(size_t)255;
        return p;
    };
    uint32_t* pk = (uint32_t*)alloc((size_t)E * 4);
    int* hist = (int*)alloc((size_t)NB * nblk * 4);
    int* btot = (int*)alloc((size_t)NB * 4);
    int* bbase = (int*)alloc((size_t)(NB + 1) * 4);
    uint32_t* ebuf = (uint32_t*)alloc((size_t)E * 4);
    int* rp = (int*)alloc((size_t)(N + 1) * 4);
    float* dinv = (float*)alloc((size_t)N * 4);
    int* ecol = (int*)alloc((size_t)E * 4);
    float* av0 = (float*)alloc((size_t)N * 4);
    float* av1 = (float*)alloc((size_t)N * 4);
    float2* bd0 = (float2*)alloc((size_t)N * 8);
    float2* bd1 = (float2*)alloc((size_t)N * 8);
    uint32_t* hb0 = (uint32_t*)alloc((size_t)N * 64 * 4);
    uint32_t* hb1 = (uint32_t*)alloc((size_t)N * 64 * 4);
    uint32_t* hb2 = (uint32_t*)alloc((size_t)N * 64 * 4);

    // ---- CSR build (row buckets; edges packed to u32 once) ----
    k_pack<<<nblk, 256, 0, stream>>>(ei, E, pk, hist, nblk, NB);
    k_scanA<<<NB, 64, 0, stream>>>(hist, nblk, btot);
    k_scanB<<<1, MAXNB, 0, stream>>>(btot, NB, bbase);
    k_binwrite<<<nblk, 256, 0, stream>>>(pk, E, hist, bbase, ebuf, nblk, NB);
    k_csr<<<NB, 256, 0, stream>>>(ebuf, bbase, rp, dinv, ecol, N, E, NB);

    // ---- hb0 = relu(x @ t1_w^T + t1_b) (bf16, MFMA) ----
    k_gemm1<<<(N + 127) / 128, 256, 0, stream>>>(x, t1w, t1b, hb0, N);

    // ---- layer 0 gate scalars ----
    k_ab<<<(N + 3) / 4, 256, 0, stream>>>(hb0, gw + 0 * 256, gb, 0, dinv, av0, bd0, N);
    // ---- layer 0: hb0 -> hb1, fused layer-1 ab ----
    k_agg<true, false><<<(N + 3) / 4, 256, 0, stream>>>(
        hb0, hb0, rp, ecol, av0, bd0, dinv, hb1, gw + 1 * 256, gb + 1, av1, bd1, N);
    // ---- layer 1: hb1 -> hb2 (raw = hb0, nontemporal) ----
    k_agg<false, true><<<(N + 3) / 4, 256, 0, stream>>>(
        hb1, hb0, rp, ecol, av1, bd1, dinv, hb2, nullptr, nullptr, nullptr, nullptr, N);

    // ---- out = log_softmax(hb2 @ t2_w^T + t2_b) (MFMA, fused) ----
    k_gemm2<<<(N + 127) / 128, 256, 0, stream>>>(hb2, t2w, t2b, out, N);
}

// Round 10
// 189.616 us; speedup vs baseline: 1.6513x; 1.0576x over previous
//
#include <hip/hip_runtime.h>
#include <math.h>

#define EPSF 0.3f
#define NPB 128      // nodes per row-bucket
#define SHB 7        // log2(NPB)
#define MAXNB 512    // max buckets (N <= 65536; packed-edge limit N < 65536)
#define CHUNK 4096   // edges per block in pack/binwrite
#define MAXSEG 8192  // LDS-staged edges per bucket in k_csr (avg ~4090)

typedef __attribute__((ext_vector_type(8))) short bf16x8;
typedef __attribute__((ext_vector_type(4))) float f32x4;

// ---------------- bf16 helpers ----------------
__device__ __forceinline__ uint32_t f2bf(float f) {
    uint32_t u = __float_as_uint(f);
    return (u + 0x7fffu + ((u >> 16) & 1u)) >> 16;  // RNE
}
__device__ __forceinline__ uint32_t pack2(float lo, float hi) {
    return f2bf(lo) | (f2bf(hi) << 16);
}
__device__ __forceinline__ float bflo(uint32_t u) { return __uint_as_float(u << 16); }
__device__ __forceinline__ float bfhi(uint32_t u) { return __uint_as_float(u & 0xffff0000u); }

// fast tanh: 1 - 2/(e^{2x}+1)
__device__ __forceinline__ float fast_tanh(float x) {
    float e = __expf(2.f * x);
    return 1.f - 2.f * __builtin_amdgcn_rcpf(e + 1.f);
}

__device__ __forceinline__ int edge_at(const int* ei, int is64, size_t idx) {
    if (is64) return (int)((const long long*)ei)[idx];
    return ei[idx];
}

__device__ __forceinline__ int detect_is64(const int* ei, int base, int E) {
    __shared__ int s_nz;
    if (threadIdx.x == 0) s_nz = 0;
    __syncthreads();
    int lim = min(512, E - base);
    int nz = 0;
    for (int t = threadIdx.x; t < lim; t += 256)
        nz |= (ei[2 * (size_t)(base + t) + 1] != 0);
    if (nz) atomicOr(&s_nz, 1);
    __syncthreads();
    return s_nz == 0;
}

// 512-entry inclusive scan in LDS (256 threads, 2 slots each); s[] must hold MAXNB ints.
__device__ __forceinline__ void scan512(int* s) {
    int t = threadIdx.x;
    for (int o = 1; o < MAXNB; o <<= 1) {
        int i2 = t + 256;
        int x1 = (t >= o) ? s[t - o] : 0;
        int x2 = (i2 >= o) ? s[i2 - o] : 0;
        __syncthreads();
        s[t] += x1;
        s[i2] += x2;
        __syncthreads();
    }
}

// ---------------- pack + bucket histogram: pk[e]=(r<<16)|c, hist[bucket][blk] ------------
__global__ __launch_bounds__(256) void k_pack(const int* __restrict__ ei, int E,
                                              uint32_t* __restrict__ pk,
                                              int* __restrict__ hist, int nblk, int NB) {
    __shared__ int lh[MAXNB];
    int base = blockIdx.x * CHUNK;
    int is64 = detect_is64(ei, base, E);
    for (int b = threadIdx.x; b < NB; b += 256) lh[b] = 0;
    __syncthreads();
    for (int j = threadIdx.x; j < CHUNK; j += 256) {
        int e = base + j;
        if (e < E) {
            int r = edge_at(ei, is64, e);
            int c = edge_at(ei, is64, (size_t)E + e);
            pk[e] = ((uint32_t)r << 16) | (uint32_t)c;
            atomicAdd(&lh[r >> SHB], 1);
        }
    }
    __syncthreads();
    for (int b = threadIdx.x; b < NB; b += 256)
        hist[(size_t)b * nblk + blockIdx.x] = lh[b];
}

// per-bucket exclusive scan across blocks (wave scan, coalesced)
__global__ void k_scanA(int* __restrict__ hist, int nblk, int* __restrict__ btot) {
    int b = blockIdx.x;
    int lane = threadIdx.x;
    int run = 0;
    for (int seg = 0; seg < nblk; seg += 64) {
        int idx = seg + lane;
        int v = (idx < nblk) ? hist[(size_t)b * nblk + idx] : 0;
        int s = v;
        for (int o = 1; o < 64; o <<= 1) {
            int t = __shfl_up(s, o);
            if (lane >= o) s += t;
        }
        if (idx < nblk) hist[(size_t)b * nblk + idx] = run + s - v;
        run += __shfl(s, 63);
    }
    if (lane == 0) btot[b] = run;
}

// scatter packed edges into bucket-ordered ebuf (bucket bases computed in-kernel)
__global__ __launch_bounds__(256) void k_binwrite(const uint32_t* __restrict__ pk, int E,
                                                  const int* __restrict__ hist,
                                                  const int* __restrict__ btot,
                                                  uint32_t* __restrict__ ebuf,
                                                  int nblk, int NB) {
    __shared__ int s[MAXNB];
    __shared__ int lcnt[MAXNB];
    int t = threadIdx.x;
    for (int b = t; b < MAXNB; b += 256) s[b] = (b < NB) ? btot[b] : 0;
    __syncthreads();
    scan512(s);
    // lcnt[b] = exclusive-prefix(btot)[b] + hist[b][blk]
    for (int b = t; b < NB; b += 256)
        lcnt[b] = s[b] - btot[b] + hist[(size_t)b * nblk + blockIdx.x];
    __syncthreads();
    int base = blockIdx.x * CHUNK;
    for (int j = t; j < CHUNK; j += 256) {
        int e = base + j;
        if (e < E) {
            uint32_t v = __builtin_nontemporal_load(&pk[e]);
            int pos = atomicAdd(&lcnt[v >> (16 + SHB)], 1);
            ebuf[pos] = v;
        }
    }
}

// one block per bucket: LDS-staged count -> rp/dinv -> scatter -> ecol
__global__ __launch_bounds__(256) void k_csr(const uint32_t* __restrict__ ebuf,
                                             const int* __restrict__ btot,
                                             int* __restrict__ rp, float* __restrict__ dinv,
                                             int* __restrict__ ecol, int N, int E, int NB) {
    __shared__ int s[MAXNB];
    __shared__ uint32_t seg[MAXSEG];
    __shared__ int cnt[NPB];
    __shared__ int sc[NPB];
    __shared__ int cur[NPB];
    int b = blockIdx.x;
    int tid = threadIdx.x;
    for (int k = tid; k < MAXNB; k += 256) s[k] = (k < NB) ? btot[k] : 0;
    __syncthreads();
    scan512(s);
    int p1 = s[b];
    int p0 = p1 - btot[b];
    int len = p1 - p0;
    bool fits = (len <= MAXSEG);
    int n0 = b << SHB;
    if (tid < NPB) cnt[tid] = 0;
    __syncthreads();
    if (fits) {
        for (int j = tid; j < len; j += 256) {
            uint32_t v = ebuf[p0 + j];
            seg[j] = v;
            atomicAdd(&cnt[(v >> 16) & (NPB - 1)], 1);
        }
    } else {
        for (int j = tid; j < len; j += 256)
            atomicAdd(&cnt[(ebuf[p0 + j] >> 16) & (NPB - 1)], 1);
    }
    __syncthreads();
    if (tid < NPB) sc[tid] = cnt[tid];
    __syncthreads();
    for (int o = 1; o < NPB; o <<= 1) {
        int v = (tid < NPB && tid >= o) ? sc[tid - o] : 0;
        __syncthreads();
        if (tid < NPB) sc[tid] += v;
        __syncthreads();
    }
    if (tid < NPB) {
        int off = sc[tid] - cnt[tid];
        cur[tid] = off;
        int node = n0 + tid;
        if (node < N) {
            rp[node] = p0 + off;
            int d = cnt[tid];
            dinv[node] = d > 0 ? rsqrtf((float)d) : 0.f;
        }
    }
    if (b == NB - 1 && tid == 0) rp[N] = E;
    __syncthreads();
    if (fits) {
        for (int j = tid; j < len; j += 256) {
            uint32_t v = seg[j];
            int pos = p0 + atomicAdd(&cur[(v >> 16) & (NPB - 1)], 1);
            ecol[pos] = (int)(v & 0xffffu);
        }
    } else {
        for (int j = tid; j < len; j += 256) {
            uint32_t v = ebuf[p0 + j];
            int pos = p0 + atomicAdd(&cur[(v >> 16) & (NPB - 1)], 1);
            ecol[pos] = (int)(v & 0xffffu);
        }
    }
}

// ---------------- GEMM1 (MFMA bf16) + fused layer-0 gate scalars ----------------
// hb = relu(x @ t1_w^T + b) as bf16; av0[i] = h.gw_i + gb[0]; bd0[i] = {h.gw_j, dinv[i]}
__global__ __launch_bounds__(256) void k_gemm1(const float* __restrict__ A,
                                               const float* __restrict__ W,
                                               const float* __restrict__ bias,
                                               uint32_t* __restrict__ hb,
                                               const float* __restrict__ gw0,
                                               const float* __restrict__ gb,
                                               const float* __restrict__ dinv,
                                               float* __restrict__ av,
                                               float2* __restrict__ bd, int M) {
    __shared__ char As[128 * 128];
    __shared__ char Bs[128 * 128];
    __shared__ float pab_a[2][128];
    __shared__ float pab_b[2][128];
    const int tid = threadIdx.x;
    const int lane = tid & 63;
    const int wave = tid >> 6;
    const int wr = wave >> 1, wc = wave & 1;
    const int m0 = blockIdx.x * 128;
    const int lrow = lane & 15, lkg = lane >> 4;
    const int sr = tid >> 3;
    const int sc = (tid & 7) * 8;

    f32x4 acc[4][4];
#pragma unroll
    for (int mi = 0; mi < 4; ++mi)
#pragma unroll
        for (int ni = 0; ni < 4; ++ni) acc[mi][ni] = (f32x4){0.f, 0.f, 0.f, 0.f};

    for (int t = 0; t < 4; ++t) {
        const int k0 = t * 64;
#pragma unroll
        for (int i = 0; i < 4; ++i) {
            int r = i * 32 + sr;
            float4 v0 = make_float4(0.f, 0.f, 0.f, 0.f), v1 = v0;
            if (m0 + r < M) {
                const float* p = &A[(size_t)(m0 + r) * 256 + k0 + sc];
                v0 = *(const float4*)p;
                v1 = *(const float4*)(p + 4);
            }
            uint4 pk = make_uint4(pack2(v0.x, v0.y), pack2(v0.z, v0.w),
                                  pack2(v1.x, v1.y), pack2(v1.z, v1.w));
            uint32_t off = (uint32_t)(r * 128 + sc * 2);
            *(uint4*)(As + (off ^ ((r & 7) << 4))) = pk;
        }
#pragma unroll
        for (int i = 0; i < 4; ++i) {
            int r = i * 32 + sr;
            const float* p = &W[(size_t)r * 256 + k0 + sc];
            float4 v0 = *(const float4*)p;
            float4 v1 = *(const float4*)(p + 4);
            uint4 pk = make_uint4(pack2(v0.x, v0.y), pack2(v0.z, v0.w),
                                  pack2(v1.x, v1.y), pack2(v1.z, v1.w));
            uint32_t off = (uint32_t)(r * 128 + sc * 2);
            *(uint4*)(Bs + (off ^ ((r & 7) << 4))) = pk;
        }
        __syncthreads();
#pragma unroll
        for (int ks = 0; ks < 2; ++ks) {
            bf16x8 af[4], bfr[4];
#pragma unroll
            for (int mi = 0; mi < 4; ++mi) {
                int r = wr * 64 + mi * 16 + lrow;
                uint32_t off = (uint32_t)(r * 128 + ks * 64 + lkg * 16);
                af[mi] = *(const bf16x8*)(As + (off ^ ((r & 7) << 4)));
            }
#pragma unroll
            for (int ni = 0; ni < 4; ++ni) {
                int r = wc * 64 + ni * 16 + lrow;
                uint32_t off = (uint32_t)(r * 128 + ks * 64 + lkg * 16);
                bfr[ni] = *(const bf16x8*)(Bs + (off ^ ((r & 7) << 4)));
            }
#pragma unroll
            for (int mi = 0; mi < 4; ++mi)
#pragma unroll
                for (int ni = 0; ni < 4; ++ni)
                    acc[mi][ni] = __builtin_amdgcn_mfma_f32_16x16x32_bf16(
                        af[mi], bfr[ni], acc[mi][ni], 0, 0, 0);
        }
        __syncthreads();
    }
    // epilogue: relu+bias -> bf16 store; fused per-row dot with gw_i/gw_j
    float bv[4], gi[4], gj[4];
#pragma unroll
    for (int ni = 0; ni < 4; ++ni) {
        int n = wc * 64 + ni * 16 + lrow;
        bv[ni] = bias[n];
        gi[ni] = gw0[n];
        gj[ni] = gw0[128 + n];
    }
#pragma unroll
    for (int mi = 0; mi < 4; ++mi) {
#pragma unroll
        for (int q = 0; q < 4; ++q) {
            float pa = 0.f, pb = 0.f;
            int m = m0 + wr * 64 + mi * 16 + lkg * 4 + q;
#pragma unroll
            for (int ni = 0; ni < 4; ++ni) {
                float v = fmaxf(acc[mi][ni][q] + bv[ni], 0.f);
                float vp = __shfl_xor(v, 1);
                if (!(lane & 1) && m < M) {
                    int n = wc * 64 + ni * 16 + lrow;
                    hb[(size_t)m * 64 + (n >> 1)] = pack2(v, vp);
                }
                pa = fmaf(v, gi[ni], pa);
                pb = fmaf(v, gj[ni], pb);
            }
#pragma unroll
            for (int o = 1; o < 16; o <<= 1) {
                pa += __shfl_xor(pa, o);
                pb += __shfl_xor(pb, o);
            }
            if (lrow == 0) {
                int rl = wr * 64 + mi * 16 + lkg * 4 + q;
                pab_a[wc][rl] = pa;
                pab_b[wc][rl] = pb;
            }
        }
    }
    __syncthreads();
    if (tid < 128) {
        int m = m0 + tid;
        if (m < M) {
            av[m] = pab_a[0][tid] + pab_a[1][tid] + gb[0];
            bd[m] = make_float2(pab_b[0][tid] + pab_b[1][tid], dinv[m]);
        }
    }
}

// ---------------- GEMM2 (MFMA bf16) + fused log_softmax ----------------
__global__ __launch_bounds__(256) void k_gemm2(const uint32_t* __restrict__ Abf,
                                               const float* __restrict__ W,
                                               const float* __restrict__ bias,
                                               float* __restrict__ out, int M) {
    __shared__ char As[128 * 128];
    __shared__ char Bs[64 * 128];
    __shared__ float redmax[2][128];
    __shared__ float redsum[2][128];
    const int tid = threadIdx.x;
    const int lane = tid & 63;
    const int wave = tid >> 6;
    const int wr = wave >> 1, wc = wave & 1;
    const int m0 = blockIdx.x * 128;
    const int lrow = lane & 15, lkg = lane >> 4;

    f32x4 acc[4][2];
#pragma unroll
    for (int mi = 0; mi < 4; ++mi)
#pragma unroll
        for (int ni = 0; ni < 2; ++ni) acc[mi][ni] = (f32x4){0.f, 0.f, 0.f, 0.f};

    for (int t = 0; t < 2; ++t) {
#pragma unroll
        for (int i = 0; i < 4; ++i) {
            int r = i * 32 + (tid >> 3);
            uint4 v = make_uint4(0u, 0u, 0u, 0u);
            if (m0 + r < M)
                v = *(const uint4*)&Abf[(size_t)(m0 + r) * 64 + t * 32 + (tid & 7) * 4];
            uint32_t off = (uint32_t)(r * 128 + (tid & 7) * 16);
            *(uint4*)(As + (off ^ ((r & 7) << 4))) = v;
        }
#pragma unroll
        for (int i = 0; i < 2; ++i) {
            int r = i * 32 + (tid >> 3);
            const float* p = &W[(size_t)r * 128 + t * 64 + (tid & 7) * 8];
            float4 v0 = *(const float4*)p, v1 = *(const float4*)(p + 4);
            uint4 pk = make_uint4(pack2(v0.x, v0.y), pack2(v0.z, v0.w),
                                  pack2(v1.x, v1.y), pack2(v1.z, v1.w));
            uint32_t off = (uint32_t)(r * 128 + (tid & 7) * 16);
            *(uint4*)(Bs + (off ^ ((r & 7) << 4))) = pk;
        }
        __syncthreads();
#pragma unroll
        for (int ks = 0; ks < 2; ++ks) {
            bf16x8 af[4], bfr[2];
#pragma unroll
            for (int mi = 0; mi < 4; ++mi) {
                int r = wr * 64 + mi * 16 + lrow;
                uint32_t off = (uint32_t)(r * 128 + ks * 64 + lkg * 16);
                af[mi] = *(const bf16x8*)(As + (off ^ ((r & 7) << 4)));
            }
#pragma unroll
            for (int ni = 0; ni < 2; ++ni) {
                int r = wc * 32 + ni * 16 + lrow;
                uint32_t off = (uint32_t)(r * 128 + ks * 64 + lkg * 16);
                bfr[ni] = *(const bf16x8*)(Bs + (off ^ ((r & 7) << 4)));
            }
#pragma unroll
            for (int mi = 0; mi < 4; ++mi)
#pragma unroll
                for (int ni = 0; ni < 2; ++ni)
                    acc[mi][ni] = __builtin_amdgcn_mfma_f32_16x16x32_bf16(
                        af[mi], bfr[ni], acc[mi][ni], 0, 0, 0);
        }
        __syncthreads();
    }

    float vb[4][2][4];
#pragma unroll
    for (int mi = 0; mi < 4; ++mi)
#pragma unroll
        for (int ni = 0; ni < 2; ++ni) {
            float bvx = bias[wc * 32 + ni * 16 + lrow];
#pragma unroll
            for (int q = 0; q < 4; ++q) vb[mi][ni][q] = acc[mi][ni][q] + bvx;
        }
#pragma unroll
    for (int mi = 0; mi < 4; ++mi)
#pragma unroll
        for (int q = 0; q < 4; ++q) {
            float mx = fmaxf(vb[mi][0][q], vb[mi][1][q]);
#pragma unroll
            for (int o = 1; o < 16; o <<= 1) mx = fmaxf(mx, __shfl_xor(mx, o));
            if (lrow == 0) redmax[wc][wr * 64 + mi * 16 + lkg * 4 + q] = mx;
        }
    __syncthreads();
    float fmv[4][4];
#pragma unroll
    for (int mi = 0; mi < 4; ++mi)
#pragma unroll
        for (int q = 0; q < 4; ++q) {
            int rl = wr * 64 + mi * 16 + lkg * 4 + q;
            float fm = fmaxf(redmax[0][rl], redmax[1][rl]);
            fmv[mi][q] = fm;
            float e = expf(vb[mi][0][q] - fm) + expf(vb[mi][1][q] - fm);
#pragma unroll
            for (int o = 1; o < 16; o <<= 1) e += __shfl_xor(e, o);
            if (lrow == 0) redsum[wc][rl] = e;
        }
    __syncthreads();
#pragma unroll
    for (int mi = 0; mi < 4; ++mi)
#pragma unroll
        for (int q = 0; q < 4; ++q) {
            int rl = wr * 64 + mi * 16 + lkg * 4 + q;
            int m = m0 + rl;
            if (m < M) {
                float ls = logf(redsum[0][rl] + redsum[1][rl]) + fmv[mi][q];
                out[(size_t)m * 64 + wc * 32 + lrow] = vb[mi][0][q] - ls;
                out[(size_t)m * 64 + wc * 32 + 16 + lrow] = vb[mi][1][q] - ls;
            }
        }
}

// ---------------- aggregation ----------------
// wave per node. Phase A: vector weight compute, pack (w_bf16<<16 | c).
// Phase B: static 16-edge windows, 4 independent uint4 gathers in flight.
// Pad edges (lane >= cnt) have wcp=0 -> w=0, c=0 (row-0 gather, L1-hot, adds 0).
template <bool FUSE_AB, bool RAW_NT>
__global__ __launch_bounds__(256) void k_agg(const uint32_t* __restrict__ hb,
                                             const uint32_t* __restrict__ raw,
                                             const int* __restrict__ rp,
                                             const int* __restrict__ ecol,
                                             const float* __restrict__ av,
                                             const float2* __restrict__ bd,
                                             const float* __restrict__ dinv,
                                             uint32_t* __restrict__ hb_out,
                                             const float* __restrict__ gw_next,
                                             const float* __restrict__ gb_next,
                                             float* __restrict__ av_out,
                                             float2* __restrict__ bd_out, int N) {
    int wid = threadIdx.x >> 6, lane = threadIdx.x & 63;
    int i = blockIdx.x * 4 + wid;
    if (i >= N) return;
    int iu = __builtin_amdgcn_readfirstlane(i);
    int p0 = __builtin_amdgcn_readfirstlane(rp[iu]);
    int p1 = __builtin_amdgcn_readfirstlane(rp[iu + 1]);
    float a_i = av[iu];
    float di = dinv[iu];
    const int lg = lane >> 4;   // edge sub-slot
    const int ll = lane & 15;   // channel quad
    const char* hbp = (const char*)hb + (ll << 4);  // per-lane gather base

    // issue raw-row load EARLY so its latency hides under the gather loop
    uint32_t r0 = 0, r1 = 0, r2 = 0, r3 = 0;
    if (lane < 16) {
        const uint32_t* rpt = raw + (size_t)i * 64 + ll * 4;
        if (RAW_NT) {
            r0 = __builtin_nontemporal_load(rpt + 0);
            r1 = __builtin_nontemporal_load(rpt + 1);
            r2 = __builtin_nontemporal_load(rpt + 2);
            r3 = __builtin_nontemporal_load(rpt + 3);
        } else {
            r0 = rpt[0]; r1 = rpt[1]; r2 = rpt[2]; r3 = rpt[3];
        }
    }

    float acc[8];
#pragma unroll
    for (int j = 0; j < 8; ++j) acc[j] = 0.f;

#define FMA8(W, U)                                                              \
    acc[0] = fmaf(W, bflo((U).x), acc[0]); acc[1] = fmaf(W, bfhi((U).x), acc[1]); \
    acc[2] = fmaf(W, bflo((U).y), acc[2]); acc[3] = fmaf(W, bfhi((U).y), acc[3]); \
    acc[4] = fmaf(W, bflo((U).z), acc[4]); acc[5] = fmaf(W, bfhi((U).z), acc[5]); \
    acc[6] = fmaf(W, bflo((U).w), acc[6]); acc[7] = fmaf(W, bfhi((U).w), acc[7]);

    for (int b0 = p0; b0 < p1; b0 += 64) {
        int cnt = min(64, p1 - b0);
        // Phase A: vector weight compute for this batch
        uint32_t wcp = 0u;
        if (lane < cnt) {
            int c = __builtin_nontemporal_load(&ecol[b0 + lane]);
            float2 t = bd[c];
            float w = fast_tanh(a_i + t.x) * t.y;
            wcp = (f2bf(w) << 16) | (uint32_t)c;
        }
        // Phase B: 16-edge windows, 4 gathers in flight
        int cntp = (cnt + 15) & ~15;
        for (int k = 0; k < cntp; k += 16) {
            int kb = (k + lg) << 2;
            uint32_t wx0 = __builtin_amdgcn_ds_bpermute(kb, (int)wcp);
            uint32_t wx1 = __builtin_amdgcn_ds_bpermute(kb + 16, (int)wcp);
            uint32_t wx2 = __builtin_amdgcn_ds_bpermute(kb + 32, (int)wcp);
            uint32_t wx3 = __builtin_amdgcn_ds_bpermute(kb + 48, (int)wcp);
            uint4 u0 = *(const uint4*)(hbp + ((wx0 & 0xffffu) << 8));
            uint4 u1 = *(const uint4*)(hbp + ((wx1 & 0xffffu) << 8));
            uint4 u2 = *(const uint4*)(hbp + ((wx2 & 0xffffu) << 8));
            uint4 u3 = *(const uint4*)(hbp + ((wx3 & 0xffffu) << 8));
            float w0 = bfhi(wx0), w1 = bfhi(wx1), w2 = bfhi(wx2), w3 = bfhi(wx3);
            FMA8(w0, u0);
            FMA8(w1, u1);
            FMA8(w2, u2);
            FMA8(w3, u3);
        }
    }
#undef FMA8
    // Phase C: reduce across the 4 edge sub-slots
#pragma unroll
    for (int j = 0; j < 8; ++j) {
        acc[j] += __shfl_xor(acc[j], 16);
        acc[j] += __shfl_xor(acc[j], 32);
    }
    // Phase D (+E): lanes 0-15 own 8 channels each
    if (lane < 16) {
        float o[8];
        o[0] = EPSF * bflo(r0) + di * acc[0]; o[1] = EPSF * bfhi(r0) + di * acc[1];
        o[2] = EPSF * bflo(r1) + di * acc[2]; o[3] = EPSF * bfhi(r1) + di * acc[3];
        o[4] = EPSF * bflo(r2) + di * acc[4]; o[5] = EPSF * bfhi(r2) + di * acc[5];
        o[6] = EPSF * bflo(r3) + di * acc[6]; o[7] = EPSF * bfhi(r3) + di * acc[7];
        uint4 w4;
        w4.x = pack2(o[0], o[1]); w4.y = pack2(o[2], o[3]);
        w4.z = pack2(o[4], o[5]); w4.w = pack2(o[6], o[7]);
        *((uint4*)(hb_out + (size_t)i * 64) + ll) = w4;
        if (FUSE_AB) {
            float pa = 0.f, pb = 0.f;
#pragma unroll
            for (int j = 0; j < 8; ++j) {
                int ch = ll * 8 + j;
                pa = fmaf(o[j], gw_next[ch], pa);
                pb = fmaf(o[j], gw_next[128 + ch], pb);
            }
#pragma unroll
            for (int off = 1; off < 16; off <<= 1) {
                pa += __shfl_xor(pa, off);
                pb += __shfl_xor(pb, off);
            }
            if (ll == 0) {
                av_out[i] = pa + gb_next[0];
                bd_out[i] = make_float2(pb, di);
            }
        }
    }
}

extern "C" void kernel_launch(void* const* d_in, const int* in_sizes, int n_in,
                              void* d_out, int out_size, void* d_ws, size_t ws_size,
                              hipStream_t stream) {
    const float* x = (const float*)d_in[0];
    const int* ei = (const int*)d_in[1];
    const float* t1w = (const float*)d_in[2];
    const float* t1b = (const float*)d_in[3];
    const float* gw = (const float*)d_in[4];
    const float* gb = (const float*)d_in[5];
    const float* t2w = (const float*)d_in[6];
    const float* t2b = (const float*)d_in[7];
    float* out = (float*)d_out;

    const int INC = 256;
    const int N = in_sizes[0] / INC;
    const int E = in_sizes[1] / 2;
    const int NB = (N + NPB - 1) >> SHB;
    const int nblk = (E + CHUNK - 1) / CHUNK;

    char* ws = (char*)d_ws;
    auto alloc = [&](size_t bytes) {
        char* p = ws;
        ws += (bytes + 255) & ~(size_t)255;
        return p;
    };
    uint32_t* pk = (uint32_t*)alloc((size_t)E * 4);
    int* hist = (int*)alloc((size_t)NB * nblk * 4);
    int* btot = (int*)alloc((size_t)NB * 4);
    uint32_t* ebuf = (uint32_t*)alloc((size_t)E * 4);
    int* rp = (int*)alloc((size_t)(N + 1) * 4);
    float* dinv = (float*)alloc((size_t)N * 4);
    int* ecol = (int*)alloc((size_t)E * 4);
    float* av0 = (float*)alloc((size_t)N * 4);
    float* av1 = (float*)alloc((size_t)N * 4);
    float2* bd0 = (float2*)alloc((size_t)N * 8);
    float2* bd1 = (float2*)alloc((size_t)N * 8);
    uint32_t* hb0 = (uint32_t*)alloc((size_t)N * 64 * 4);
    uint32_t* hb1 = (uint32_t*)alloc((size_t)N * 64 * 4);
    uint32_t* hb2 = (uint32_t*)alloc((size_t)N * 64 * 4);

    // ---- CSR build (row buckets; edges packed to u32 once; bases computed in-kernel) ----
    k_pack<<<nblk, 256, 0, stream>>>(ei, E, pk, hist, nblk, NB);
    k_scanA<<<NB, 64, 0, stream>>>(hist, nblk, btot);
    k_binwrite<<<nblk, 256, 0, stream>>>(pk, E, hist, btot, ebuf, nblk, NB);
    k_csr<<<NB, 256, 0, stream>>>(ebuf, btot, rp, dinv, ecol, N, E, NB);

    // ---- hb0 = relu(x @ t1_w^T + t1_b) (bf16, MFMA) + layer-0 gate scalars ----
    k_gemm1<<<(N + 127) / 128, 256, 0, stream>>>(x, t1w, t1b, hb0,
                                                 gw + 0 * 256, gb, dinv, av0, bd0, N);

    // ---- layer 0: hb0 -> hb1, fused layer-1 gate scalars ----
    k_agg<true, false><<<(N + 3) / 4, 256, 0, stream>>>(
        hb0, hb0, rp, ecol, av0, bd0, dinv, hb1, gw + 1 * 256, gb + 1, av1, bd1, N);
    // ---- layer 1: hb1 -> hb2 (raw = hb0, nontemporal) ----
    k_agg<false, true><<<(N + 3) / 4, 256, 0, stream>>>(
        hb1, hb0, rp, ecol, av1, bd1, dinv, hb2, nullptr, nullptr, nullptr, nullptr, N);

    // ---- out = log_softmax(hb2 @ t2_w^T + t2_b) (MFMA, fused) ----
    k_gemm2<<<(N + 127) / 128, 256, 0, stream>>>(hb2, t2w, t2b, out, N);
}